// Round 11
// baseline (296.686 us; speedup 1.0000x reference)
//
#include <hip/hip_runtime.h>

#define NS 7
#define NK 6
#define TW 294    // torsion row width = NS*NS*NK
#define TPB 32    // triplets per tile
#define NTILES 4  // tiles per block (software pipeline depth)

typedef float f4 __attribute__((ext_vector_type(4)));

// Zeros of spherical Bessel j_l, l=1..6, k=1..6 (accurate to ~1e-7; the same
// values the reference's bisection converges to, rounded to f32).
__constant__ float ZG[6][6] = {
    {4.4934095f, 7.7252518f, 10.9041217f, 14.0661939f, 17.2207553f, 20.3713030f},
    {5.7634592f, 9.0950113f, 12.3229410f, 15.5146030f, 18.6890364f, 21.8538742f},
    {6.9879320f, 10.4171185f, 13.6980232f, 16.9236213f, 20.1218062f, 23.3042470f},
    {8.1825615f, 11.7049072f, 15.0396647f, 18.3012560f, 21.5254177f, 24.7275655f},
    {9.3558121f, 12.9665302f, 16.3547096f, 19.6531521f, 22.9045506f, 26.1277501f},
    {10.5128354f, 14.2073925f, 17.6479743f, 20.9834631f, 24.2627681f, 27.5078684f}
};

// j_{l-1}, j_l at x via upward recurrence, fast HW trig.
__device__ __forceinline__ void jl_pair_fast(float x, int l, float* jlm1, float* jl) {
    float s = __sinf(x), c = __cosf(x);
    float inv = 1.0f / x;
    float jm = c * inv;   // j_{-1}
    float j = s * inv;    // j_0
    for (int ll = 1; ll <= l; ++ll) {
        float t = (float)(2 * ll - 1) * inv * j - jm;
        jm = j;
        j = t;
    }
    *jlm1 = jm;
    *jl = j;
}

__device__ __forceinline__ void compute_tile(
    int t0, int T,
    const float* __restrict__ angle, const float* __restrict__ torsion,
    const float* __restrict__ dist, const int* __restrict__ idx_kj,
    const float* __restrict__ zc, const float* __restrict__ nc,
    const float* __restrict__ Kc,
    float* __restrict__ rbf, float* __restrict__ cbf, int tid)
{
    if (tid < TPB) {
        // cbf[49] for triplet slot `tid`, m-major (3-deep P chain)
        int t = t0 + tid;
        int tc = t < T ? t : T - 1;
        float ang = angle[tc];
        float phi = torsion[tc];

        float st = __sinf(ang), ct = __cosf(ang);
        float sp = __sinf(phi), cp = __cosf(phi);
        float sm[NS], cm[NS];
        sm[1] = sp; cm[1] = cp;
        #pragma unroll
        for (int m = 2; m < NS; ++m) {
            sm[m] = sm[m - 1] * cp + cm[m - 1] * sp;
            cm[m] = cm[m - 1] * cp - sm[m - 1] * sp;
        }

        float* cb = cbf + tid * 49;
        float pmm = 1.0f;  // P[m][m]
        #pragma unroll
        for (int m = 0; m < NS; ++m) {
            if (m > 0) pmm = (float)(1 - 2 * m) * pmm * st;
            {
                int f = m * m + m;
                if (m == 0) cb[f] = Kc[f];
                else {
                    cb[f + m] = Kc[f + m] * cm[m] * pmm;
                    cb[f - m] = Kc[f - m] * sm[m] * pmm;
                }
            }
            if (m < NS - 1) {
                float plm1 = pmm;
                float pl = (float)(2 * m + 1) * ct * pmm;  // P[m+1][m]
                {
                    int l = m + 1, f = l * l + l;
                    if (m == 0) cb[f] = Kc[f] * pl;
                    else {
                        cb[f + m] = Kc[f + m] * cm[m] * pl;
                        cb[f - m] = Kc[f - m] * sm[m] * pl;
                    }
                }
                #pragma unroll
                for (int l = m + 2; l < NS; ++l) {
                    float pn = ((float)(2 * l - 1) * ct * pl -
                                (float)(l + m - 1) * plm1) / (float)(l - m);
                    plm1 = pl; pl = pn;
                    int f = l * l + l;
                    if (m == 0) cb[f] = Kc[f] * pl;
                    else {
                        cb[f + m] = Kc[f + m] * cm[m] * pl;
                        cb[f - m] = Kc[f - m] * sm[m] * pl;
                    }
                }
            }
        }
    } else if (tid >= 64 && tid < 64 + 6 * TPB) {
        // rbf: 6 threads per triplet, 7 Bessel evals each (fast trig)
        int w = tid - 64;
        int s = w / 6, p = w - 6 * s;
        int t = t0 + s;
        int tc = t < T ? t : T - 1;
        int idx = idx_kj[tc];
        float x = dist[idx] * 0.2f;
        int jlo = p * 7;
        for (int jj = jlo; jj < jlo + 7; ++jj) {
            int l = jj / 6;
            float arg = zc[jj] * x;
            float s1 = __sinf(arg), c1 = __cosf(arg);
            float inv = 1.0f / arg;
            float j0 = s1 * inv;
            float val = j0;
            if (l >= 1) {
                float jm = j0;
                float jcur = (s1 * inv - c1) * inv;
                for (int ll = 2; ll <= l; ++ll) {
                    float tmp = (float)(2 * ll - 1) * inv * jcur - jm;
                    jm = jcur;
                    jcur = tmp;
                }
                val = jcur;
            }
            rbf[s * 44 + jj] = nc[jj] * val;
        }
    }
}

__device__ __forceinline__ void store_tile(
    int t0, int T, const float* __restrict__ rbf, const float* __restrict__ cbf,
    float* __restrict__ outA, float* __restrict__ outT, int tid)
{
    int nvalid = T - t0; if (nvalid > TPB) nvalid = TPB;
    if (nvalid == TPB) {
        // register products -> flat nontemporal dwordx4 stores.
        // Even col-pair shares a = c/42 and q = a*7 + (c%42)/6 (q never splits a pair).
        f4* __restrict__ gT = (f4*)(outT + (size_t)t0 * TW);
        unsigned row = (unsigned)(4 * tid) / 294u;
        unsigned c   = (unsigned)(4 * tid) - row * 294u;
        #pragma unroll
        for (int it = 0; it < 10; ++it) {
            if (it < 9 || tid < 48) {
                unsigned row1 = row, c1 = c + 2;
                if (c1 >= 294u) { c1 -= 294u; row1 += 1; }
                unsigned a0 = c / 42u,  r0 = c - a0 * 42u,  q0 = a0 * 7u + r0 / 6u;
                unsigned a1 = c1 / 42u, r1 = c1 - a1 * 42u, q1 = a1 * 7u + r1 / 6u;
                float qv0 = cbf[row * 49 + q0];
                float2 rv0 = *(const float2*)&rbf[row * 44 + r0];
                float qv1 = cbf[row1 * 49 + q1];
                float2 rv1 = *(const float2*)&rbf[row1 * 44 + r1];
                f4 val = { qv0 * rv0.x, qv0 * rv0.y, qv1 * rv1.x, qv1 * rv1.y };
                __builtin_nontemporal_store(val, gT + it * 256 + tid);
            }
            c += 142u; row += 3u;
            if (c >= 294u) { c -= 294u; row += 1u; }
        }
        f4* __restrict__ gA = (f4*)(outA + (size_t)t0 * 42);
        unsigned arow = (unsigned)(4 * tid) / 42u;
        unsigned ac   = (unsigned)(4 * tid) - arow * 42u;
        #pragma unroll
        for (int it = 0; it < 2; ++it) {
            if (it < 1 || tid < 80) {
                unsigned arow1 = arow, ac1 = ac + 2;
                if (ac1 >= 42u) { ac1 -= 42u; arow1 += 1; }
                unsigned l0 = ac / 6u,  qa0 = l0 * l0 + l0;
                unsigned l1 = ac1 / 6u, qa1 = l1 * l1 + l1;
                float qv0 = cbf[arow * 49 + qa0];
                float2 rv0 = *(const float2*)&rbf[arow * 44 + ac];
                float qv1 = cbf[arow1 * 49 + qa1];
                float2 rv1 = *(const float2*)&rbf[arow1 * 44 + ac1];
                f4 val = { qv0 * rv0.x, qv0 * rv0.y, qv1 * rv1.x, qv1 * rv1.y };
                __builtin_nontemporal_store(val, gA + it * 256 + tid);
            }
            ac += 16u; arow += 24u;  // +1024 floats = 24*42 + 16
            if (ac >= 42u) { ac -= 42u; arow += 1u; }
        }
    } else {
        // partial tail tile (not hit when T % TPB == 0) — safe scalar path
        for (int g = tid; g < nvalid * TW; g += 256) {
            int row = g / TW, cc = g - row * TW;
            int a = cc / 42, r = cc - a * 42;
            outT[(size_t)t0 * TW + g] = cbf[row * 49 + a * 7 + r / 6] * rbf[row * 44 + r];
        }
        for (int g = tid; g < nvalid * 42; g += 256) {
            int row = g / 42, r = g - row * 42;
            int l = r / 6;
            outA[(size_t)t0 * 42 + g] = cbf[row * 49 + l * l + l] * rbf[row * 44 + r];
        }
    }
}

__launch_bounds__(256, 4)
__global__ void fused_kernel(const float* __restrict__ dist,
                             const float* __restrict__ angle,
                             const float* __restrict__ torsion,
                             const float* __restrict__ freq,
                             const int* __restrict__ idx_kj,
                             float* __restrict__ outD,
                             float* __restrict__ outA,
                             float* __restrict__ outT,
                             int E, int T, int NBLK_T, int NBTILES) {
    // smem: buf0[2976] (rbf 32x44 + cbf 32x49), buf1[2976], zc[42] nc[42] Kc[49]
    __shared__ __align__(16) float smem[2 * 2976 + 133];
    const int tid = threadIdx.x;

    if (blockIdx.x >= NBLK_T) {
        // ================= dist-embedding path =================
        const int e0 = (blockIdx.x - NBLK_T) * 256;
        int e = e0 + tid;
        int ec = e < E ? e : E - 1;
        float x = dist[ec] * 0.2f;
        float inv = 1.0f / x;
        float x2 = x * x;
        float xp0 = x2 * x2 * x;  // x^5
        float env = inv - 28.0f * xp0 + 48.0f * xp0 * x - 21.0f * xp0 * x2;
        float v[NK];
        #pragma unroll
        for (int i = 0; i < NK; ++i) v[i] = env * __sinf(freq[i] * x);
        if (e0 + 256 <= E) {
            #pragma unroll
            for (int i = 0; i < NK; ++i) smem[tid * 6 + i] = v[i];
            __syncthreads();
            const f4* b4 = (const f4*)smem;
            f4* o4 = (f4*)(outD + (size_t)e0 * 6);
            __builtin_nontemporal_store(b4[tid], o4 + tid);
            if (tid < 128) __builtin_nontemporal_store(b4[256 + tid], o4 + 256 + tid);
        } else if (e < E) {
            #pragma unroll
            for (int i = 0; i < NK; ++i) outD[(size_t)e * 6 + i] = v[i];
        }
        return;
    }

    // ================= triplet path (4-tile software pipeline) =================
    float* buf0 = smem;
    float* buf1 = smem + 2976;
    float* zc = smem + 5952;   // 42
    float* nc = zc + 42;       // 42
    float* Kc = nc + 42;       // 49

    // ---- phase 0: constant tables (once per block, amortized over NTILES tiles)
    if (tid < 42) {
        int l = tid / 6, i = tid - 6 * l;
        float z = (l == 0) ? (float)(i + 1) * 3.14159265358979f : ZG[l - 1][i];
        float jm, jv;
        jl_pair_fast(z, l + 1, &jm, &jv);   // jv = j_{l+1}(z)
        zc[tid] = z;
        nc[tid] = 1.41421356237309f / fabsf(jv);
    } else if (tid >= 64 && tid < 113) {
        int f = tid - 64;
        int l = 0;
        while ((l + 1) * (l + 1) <= f) ++l;
        int m = f - l * l - l;
        int am = m < 0 ? -m : m;
        float ratio = 1.0f;
        for (int t = l - am + 1; t <= l + am; ++t) ratio /= (float)t;
        float K = sqrtf((float)(2 * l + 1) * 0.07957747154594767f * ratio);
        if (m != 0) K *= 1.41421356237309505f;
        Kc[f] = K;
    }
    const int tilebase = blockIdx.x * NTILES;
    __syncthreads();

    // prologue: compute tile 0 into buf0
    compute_tile(tilebase * TPB, T, angle, torsion, dist, idx_kj,
                 zc, nc, Kc, buf0, buf0 + 1408, tid);
    __syncthreads();

    for (int k = 0; k < NTILES; ++k) {
        int tile = tilebase + k;
        if (tile >= NBTILES) break;
        float* bc = (k & 1) ? buf1 : buf0;
        float* bn = (k & 1) ? buf0 : buf1;
        // issue tile k's stores (fire-and-forget), then compute tile k+1
        store_tile(tile * TPB, T, bc, bc + 1408, outA, outT, tid);
        if (k + 1 < NTILES && tile + 1 < NBTILES)
            compute_tile((tile + 1) * TPB, T, angle, torsion, dist, idx_kj,
                         zc, nc, Kc, bn, bn + 1408, tid);
        __syncthreads();
    }
}

extern "C" void kernel_launch(void* const* d_in, const int* in_sizes, int n_in,
                              void* d_out, int out_size, void* d_ws, size_t ws_size,
                              hipStream_t stream) {
    const float* dist    = (const float*)d_in[0];
    const float* angle   = (const float*)d_in[1];
    const float* torsion = (const float*)d_in[2];
    const float* freq    = (const float*)d_in[3];
    const int*   idx_kj  = (const int*)d_in[4];
    const int E = in_sizes[0];
    const int T = in_sizes[1];
    float* out = (float*)d_out;
    float* outA = out + (size_t)E * NK;
    float* outT = outA + (size_t)T * 42;

    const int NBTILES = (T + TPB - 1) / TPB;
    const int NBLK_T = (NBTILES + NTILES - 1) / NTILES;
    const int NBD = (E + 255) / 256;
    fused_kernel<<<NBLK_T + NBD, 256, 0, stream>>>(dist, angle, torsion, freq, idx_kj,
                                                   out, outA, outT, E, T, NBLK_T, NBTILES);
}

// Round 12
// 157.466 us; speedup vs baseline: 1.8841x; 1.8841x over previous
//
#include <hip/hip_runtime.h>
#include <math.h>

#define NS 7
#define NK 6
#define TW 294   // torsion row width = NS*NS*NK
#define TPB 32   // triplets per block

typedef float f4 __attribute__((ext_vector_type(4)));

struct ConstTables {
    float zc[42];   // Bessel zeros z_{l,i}
    float nc[42];   // sqrt(2)/|j_{l+1}(z)|
    float Kc[49];   // real-SH normalization, flat f = l*l+l+m
};

__launch_bounds__(256, 8)
__global__ void fused_kernel(const float* __restrict__ dist,
                             const float* __restrict__ angle,
                             const float* __restrict__ torsion,
                             const float* __restrict__ freq,
                             const int* __restrict__ idx_kj,
                             float* __restrict__ outD,
                             float* __restrict__ outA,
                             float* __restrict__ outT,
                             int E, int T, int NBD,
                             ConstTables ct) {
    // smem union: triplet path rbf[32][44] @0, cbf[32][49] @1408; dist buf[1536] @0
    __shared__ __align__(16) float smem[2976];
    const int tid = threadIdx.x;

    if (blockIdx.x < NBD) {
        // ================= dist-embedding path (runs first, overlaps triplet warm-up) ====
        const int e0 = blockIdx.x * 256;
        int e = e0 + tid;
        int ec = e < E ? e : E - 1;
        float x = dist[ec] * 0.2f;
        float inv = 1.0f / x;
        float x2 = x * x;
        float xp0 = x2 * x2 * x;  // x^5
        float env = inv - 28.0f * xp0 + 48.0f * xp0 * x - 21.0f * xp0 * x2;
        float v[NK];
        #pragma unroll
        for (int i = 0; i < NK; ++i) v[i] = env * __sinf(freq[i] * x);
        if (e0 + 256 <= E) {
            #pragma unroll
            for (int i = 0; i < NK; ++i) smem[tid * 6 + i] = v[i];
            __syncthreads();
            const f4* b4 = (const f4*)smem;
            f4* o4 = (f4*)(outD + (size_t)e0 * 6);
            __builtin_nontemporal_store(b4[tid], o4 + tid);
            if (tid < 128) __builtin_nontemporal_store(b4[256 + tid], o4 + 256 + tid);
        } else if (e < E) {
            #pragma unroll
            for (int i = 0; i < NK; ++i) outD[(size_t)e * 6 + i] = v[i];
        }
        return;
    }

    // ================= triplet path =================
    float* __restrict__ rbf_s = smem;          // [32][44]
    float* __restrict__ cbf_s = smem + 1408;   // [32][49]
    const int t0 = (blockIdx.x - NBD) * TPB;

    // ---- phase 1
    if (tid < TPB) {
        // cbf[49] for triplet slot `tid`, m-major (3-deep P chain)
        int t = t0 + tid;
        int tc = t < T ? t : T - 1;
        float ang = angle[tc];
        float phi = torsion[tc];

        float st = __sinf(ang), ct_ = __cosf(ang);
        float sp = __sinf(phi), cp = __cosf(phi);
        float sm[NS], cm[NS];
        sm[1] = sp; cm[1] = cp;
        #pragma unroll
        for (int m = 2; m < NS; ++m) {
            sm[m] = sm[m - 1] * cp + cm[m - 1] * sp;
            cm[m] = cm[m - 1] * cp - sm[m - 1] * sp;
        }

        float* cb = cbf_s + tid * 49;
        float pmm = 1.0f;  // P[m][m]
        #pragma unroll
        for (int m = 0; m < NS; ++m) {
            if (m > 0) pmm = (float)(1 - 2 * m) * pmm * st;
            {
                int f = m * m + m;
                if (m == 0) cb[f] = ct.Kc[f];
                else {
                    cb[f + m] = ct.Kc[f + m] * cm[m] * pmm;
                    cb[f - m] = ct.Kc[f - m] * sm[m] * pmm;
                }
            }
            if (m < NS - 1) {
                float plm1 = pmm;
                float pl = (float)(2 * m + 1) * ct_ * pmm;  // P[m+1][m]
                {
                    int l = m + 1, f = l * l + l;
                    if (m == 0) cb[f] = ct.Kc[f] * pl;
                    else {
                        cb[f + m] = ct.Kc[f + m] * cm[m] * pl;
                        cb[f - m] = ct.Kc[f - m] * sm[m] * pl;
                    }
                }
                #pragma unroll
                for (int l = m + 2; l < NS; ++l) {
                    float pn = ((float)(2 * l - 1) * ct_ * pl -
                                (float)(l + m - 1) * plm1) / (float)(l - m);
                    plm1 = pl; pl = pn;
                    int f = l * l + l;
                    if (m == 0) cb[f] = ct.Kc[f] * pl;
                    else {
                        cb[f + m] = ct.Kc[f + m] * cm[m] * pl;
                        cb[f - m] = ct.Kc[f - m] * sm[m] * pl;
                    }
                }
            }
        }
    } else if (tid >= 64 && tid < 64 + 6 * TPB) {
        // rbf: 6 threads per triplet, 7 Bessel evals each (fast HW trig)
        int w = tid - 64;
        int s = w / 6, p = w - 6 * s;
        int t = t0 + s;
        int tc = t < T ? t : T - 1;
        int idx = idx_kj[tc];
        float x = dist[idx] * 0.2f;
        int jlo = p * 7;
        for (int jj = jlo; jj < jlo + 7; ++jj) {
            int l = jj / 6;
            float arg = ct.zc[jj] * x;
            float s1 = __sinf(arg), c1 = __cosf(arg);
            float inv = 1.0f / arg;
            float j0 = s1 * inv;
            float val = j0;
            if (l >= 1) {
                float jm = j0;
                float jcur = (s1 * inv - c1) * inv;
                for (int ll = 2; ll <= l; ++ll) {
                    float tmp = (float)(2 * ll - 1) * inv * jcur - jm;
                    jm = jcur;
                    jcur = tmp;
                }
                val = jcur;
            }
            rbf_s[s * 44 + jj] = ct.nc[jj] * val;
        }
    }
    __syncthreads();

    int nvalid = T - t0; if (nvalid > TPB) nvalid = TPB;

    if (nvalid == TPB) {
        // ---- phase 2: register products -> flat nontemporal dwordx4 stores.
        // Even col-pair shares a = c/42 and q = a*7 + (c%42)/6 (q never splits a pair).
        f4* __restrict__ gT = (f4*)(outT + (size_t)t0 * TW);
        unsigned row = (unsigned)(4 * tid) / 294u;
        unsigned c   = (unsigned)(4 * tid) - row * 294u;
        #pragma unroll
        for (int it = 0; it < 10; ++it) {
            if (it < 9 || tid < 48) {
                unsigned row1 = row, c1 = c + 2;
                if (c1 >= 294u) { c1 -= 294u; row1 += 1; }
                unsigned a0 = c / 42u,  r0 = c - a0 * 42u,  q0 = a0 * 7u + r0 / 6u;
                unsigned a1 = c1 / 42u, r1 = c1 - a1 * 42u, q1 = a1 * 7u + r1 / 6u;
                float qv0 = cbf_s[row * 49 + q0];
                float2 rv0 = *(const float2*)&rbf_s[row * 44 + r0];
                float qv1 = cbf_s[row1 * 49 + q1];
                float2 rv1 = *(const float2*)&rbf_s[row1 * 44 + r1];
                f4 val = { qv0 * rv0.x, qv0 * rv0.y, qv1 * rv1.x, qv1 * rv1.y };
                __builtin_nontemporal_store(val, gT + it * 256 + tid);
            }
            c += 142u; row += 3u;
            if (c >= 294u) { c -= 294u; row += 1u; }
        }
        f4* __restrict__ gA = (f4*)(outA + (size_t)t0 * 42);
        unsigned arow = (unsigned)(4 * tid) / 42u;
        unsigned ac   = (unsigned)(4 * tid) - arow * 42u;
        #pragma unroll
        for (int it = 0; it < 2; ++it) {
            if (it < 1 || tid < 80) {
                unsigned arow1 = arow, ac1 = ac + 2;
                if (ac1 >= 42u) { ac1 -= 42u; arow1 += 1; }
                unsigned l0 = ac / 6u,  qa0 = l0 * l0 + l0;
                unsigned l1 = ac1 / 6u, qa1 = l1 * l1 + l1;
                float qv0 = cbf_s[arow * 49 + qa0];
                float2 rv0 = *(const float2*)&rbf_s[arow * 44 + ac];
                float qv1 = cbf_s[arow1 * 49 + qa1];
                float2 rv1 = *(const float2*)&rbf_s[arow1 * 44 + ac1];
                f4 val = { qv0 * rv0.x, qv0 * rv0.y, qv1 * rv1.x, qv1 * rv1.y };
                __builtin_nontemporal_store(val, gA + it * 256 + tid);
            }
            ac += 16u; arow += 24u;  // +1024 floats = 24*42 + 16
            if (ac >= 42u) { ac -= 42u; arow += 1u; }
        }
    } else {
        // partial tail block (not hit when T % TPB == 0) — safe scalar path
        for (int g = tid; g < nvalid * TW; g += 256) {
            int row = g / TW, cc = g - row * TW;
            int a = cc / 42, r = cc - a * 42;
            outT[(size_t)t0 * TW + g] = cbf_s[row * 49 + a * 7 + r / 6] * rbf_s[row * 44 + r];
        }
        for (int g = tid; g < nvalid * 42; g += 256) {
            int row = g / 42, r = g - row * 42;
            int l = r / 6;
            outA[(size_t)t0 * 42 + g] = cbf_s[row * 49 + l * l + l] * rbf_s[row * 44 + r];
        }
    }
}

// ---- host-side double-precision table computation (pure CPU math; graph-safe) ----
static double jl_host(double x, int n) {
    double j0 = sin(x) / x;
    if (n == 0) return j0;
    double jm = j0, j = sin(x) / (x * x) - cos(x) / x;
    for (int l = 2; l <= n; ++l) {
        double t = (2.0 * l - 1.0) / x * j - jm;
        jm = j;
        j = t;
    }
    return j;
}

static void compute_tables(ConstTables* ct) {
    const double PI = 3.14159265358979323846;
    double zeros[NS][12];
    const int total = NK + NS - 1;  // 12
    for (int i = 0; i < total; ++i) zeros[0][i] = (i + 1) * PI;
    for (int l = 1; l < NS; ++l) {
        for (int i = 0; i < total - l; ++i) {
            double a = zeros[l - 1][i], b = zeros[l - 1][i + 1];
            double fa = jl_host(a, l);
            for (int it = 0; it < 100; ++it) {
                double m = 0.5 * (a + b);
                double fm = jl_host(m, l);
                if (fa * fm <= 0.0) b = m;
                else { a = m; fa = fm; }
            }
            zeros[l][i] = 0.5 * (a + b);
        }
    }
    for (int l = 0; l < NS; ++l) {
        for (int i = 0; i < NK; ++i) {
            double z = zeros[l][i];
            double jn1 = jl_host(z, l + 1);
            ct->zc[l * 6 + i] = (float)z;
            ct->nc[l * 6 + i] = (float)(1.0 / sqrt(0.5 * jn1 * jn1));
        }
    }
    double fact[13];
    fact[0] = 1.0;
    for (int i = 1; i < 13; ++i) fact[i] = fact[i - 1] * (double)i;
    ct->Kc[0] = (float)(0.5 / sqrt(PI));
    for (int l = 1; l < NS; ++l) {
        for (int m = -l; m <= l; ++m) {
            int am = m < 0 ? -m : m;
            double K = sqrt((2.0 * l + 1.0) / (4.0 * PI) * fact[l - am] / fact[l + am]);
            if (m != 0) K *= sqrt(2.0);
            ct->Kc[l * l + m + l] = (float)K;
        }
    }
}

extern "C" void kernel_launch(void* const* d_in, const int* in_sizes, int n_in,
                              void* d_out, int out_size, void* d_ws, size_t ws_size,
                              hipStream_t stream) {
    const float* dist    = (const float*)d_in[0];
    const float* angle   = (const float*)d_in[1];
    const float* torsion = (const float*)d_in[2];
    const float* freq    = (const float*)d_in[3];
    const int*   idx_kj  = (const int*)d_in[4];
    const int E = in_sizes[0];
    const int T = in_sizes[1];
    float* out = (float*)d_out;
    float* outA = out + (size_t)E * NK;
    float* outT = outA + (size_t)T * 42;

    ConstTables ct;
    compute_tables(&ct);

    const int NBT = (T + TPB - 1) / TPB;
    const int NBD = (E + 255) / 256;
    fused_kernel<<<NBD + NBT, 256, 0, stream>>>(dist, angle, torsion, freq, idx_kj,
                                                out, outA, outT, E, T, NBD, ct);
}

// Round 13
// 145.216 us; speedup vs baseline: 2.0431x; 1.0844x over previous
//
#include <hip/hip_runtime.h>
#include <math.h>

#define NS 7
#define NK 6
#define TW 294   // torsion row width = NS*NS*NK
#define TPW 8    // triplets per wave
#define TPB 32   // triplets per block (4 waves)

typedef float f4 __attribute__((ext_vector_type(4)));

struct ConstTables {
    float zc[42];   // Bessel zeros z_{l,i}
    float nc[42];   // sqrt(2)/|j_{l+1}(z)|
    float Kc[49];   // real-SH normalization, flat f = l*l+l+m
};

__launch_bounds__(256, 8)
__global__ void fused_kernel(const float* __restrict__ dist,
                             const float* __restrict__ angle,
                             const float* __restrict__ torsion,
                             const float* __restrict__ freq,
                             const int* __restrict__ idx_kj,
                             float* __restrict__ outD,
                             float* __restrict__ outA,
                             float* __restrict__ outT,
                             int E, int T, int NBD,
                             ConstTables ct) {
    // smem union: triplet path 4 wave-slices x 744 floats (rbf[8][44] + cbf[8][49]);
    // dist path buf[1536]
    __shared__ __align__(16) float smem[2976];
    const int tid = threadIdx.x;

    if (blockIdx.x < NBD) {
        // ================= dist-embedding path (first in grid) =================
        const int e0 = blockIdx.x * 256;
        int e = e0 + tid;
        int ec = e < E ? e : E - 1;
        float x = dist[ec] * 0.2f;
        float inv = 1.0f / x;
        float x2 = x * x;
        float xp0 = x2 * x2 * x;  // x^5
        float env = inv - 28.0f * xp0 + 48.0f * xp0 * x - 21.0f * xp0 * x2;
        float v[NK];
        #pragma unroll
        for (int i = 0; i < NK; ++i) v[i] = env * __sinf(freq[i] * x);
        if (e0 + 256 <= E) {
            #pragma unroll
            for (int i = 0; i < NK; ++i) smem[tid * 6 + i] = v[i];
            __syncthreads();
            const f4* b4 = (const f4*)smem;
            f4* o4 = (f4*)(outD + (size_t)e0 * 6);
            __builtin_nontemporal_store(b4[tid], o4 + tid);
            if (tid < 128) __builtin_nontemporal_store(b4[256 + tid], o4 + 256 + tid);
        } else if (e < E) {
            #pragma unroll
            for (int i = 0; i < NK; ++i) outD[(size_t)e * 6 + i] = v[i];
        }
        return;
    }

    // ================= triplet path: barrier-free, wave-independent =================
    const int w = tid >> 6, lane = tid & 63;
    float* __restrict__ rbf_s = smem + w * 744;        // [8][44]
    float* __restrict__ cbf_s = smem + w * 744 + 352;  // [8][49]
    const int t0w = (blockIdx.x - NBD) * TPB + w * TPW;

    // ---- phase 1 (within-wave)
    if (lane < TPW) {
        // cbf[49] for triplet slot `lane`, m-major (3-deep P chain)
        int t = t0w + lane;
        int tc = t < T ? t : T - 1;
        float ang = angle[tc];
        float phi = torsion[tc];

        float st = __sinf(ang), ct_ = __cosf(ang);
        float sp = __sinf(phi), cp = __cosf(phi);
        float sm[NS], cm[NS];
        sm[1] = sp; cm[1] = cp;
        #pragma unroll
        for (int m = 2; m < NS; ++m) {
            sm[m] = sm[m - 1] * cp + cm[m - 1] * sp;
            cm[m] = cm[m - 1] * cp - sm[m - 1] * sp;
        }

        float* cb = cbf_s + lane * 49;
        float pmm = 1.0f;  // P[m][m]
        #pragma unroll
        for (int m = 0; m < NS; ++m) {
            if (m > 0) pmm = (float)(1 - 2 * m) * pmm * st;
            {
                int f = m * m + m;
                if (m == 0) cb[f] = ct.Kc[f];
                else {
                    cb[f + m] = ct.Kc[f + m] * cm[m] * pmm;
                    cb[f - m] = ct.Kc[f - m] * sm[m] * pmm;
                }
            }
            if (m < NS - 1) {
                float plm1 = pmm;
                float pl = (float)(2 * m + 1) * ct_ * pmm;  // P[m+1][m]
                {
                    int l = m + 1, f = l * l + l;
                    if (m == 0) cb[f] = ct.Kc[f] * pl;
                    else {
                        cb[f + m] = ct.Kc[f + m] * cm[m] * pl;
                        cb[f - m] = ct.Kc[f - m] * sm[m] * pl;
                    }
                }
                #pragma unroll
                for (int l = m + 2; l < NS; ++l) {
                    float pn = ((float)(2 * l - 1) * ct_ * pl -
                                (float)(l + m - 1) * plm1) / (float)(l - m);
                    plm1 = pl; pl = pn;
                    int f = l * l + l;
                    if (m == 0) cb[f] = ct.Kc[f] * pl;
                    else {
                        cb[f + m] = ct.Kc[f + m] * cm[m] * pl;
                        cb[f - m] = ct.Kc[f - m] * sm[m] * pl;
                    }
                }
            }
        }
    } else if (lane >= 16) {
        // rbf: 6 lanes per triplet, 7 Bessel evals each (fast HW trig)
        int ww = lane - 16;
        int s = ww / 6, p = ww - 6 * s;
        int t = t0w + s;
        int tc = t < T ? t : T - 1;
        int idx = idx_kj[tc];
        float x = dist[idx] * 0.2f;
        int jlo = p * 7;
        for (int jj = jlo; jj < jlo + 7; ++jj) {
            int l = jj / 6;
            float arg = ct.zc[jj] * x;
            float s1 = __sinf(arg), c1 = __cosf(arg);
            float inv = 1.0f / arg;
            float j0 = s1 * inv;
            float val = j0;
            if (l >= 1) {
                float jm = j0;
                float jcur = (s1 * inv - c1) * inv;
                for (int ll = 2; ll <= l; ++ll) {
                    float tmp = (float)(2 * ll - 1) * inv * jcur - jm;
                    jm = jcur;
                    jcur = tmp;
                }
                val = jcur;
            }
            rbf_s[s * 44 + jj] = ct.nc[jj] * val;
        }
    }
    // within-wave LDS handoff: drain this wave's ds_writes; no block barrier.
    asm volatile("s_waitcnt lgkmcnt(0)" ::: "memory");
    __builtin_amdgcn_sched_barrier(0);

    int nvalid = T - t0w; if (nvalid > TPW) nvalid = TPW;

    if (nvalid == TPW) {
        // ---- phase 2: register products -> flat nontemporal dwordx4 stores.
        // Wave tile = 8 rows x 294 = 588 f4 chunks; +8 x 42 = 84 f4 chunks (angle).
        // Even col-pair shares a = c/42 and q = a*7 + (c%42)/6 (q never splits a pair).
        f4* __restrict__ gT = (f4*)(outT + (size_t)t0w * TW);
        unsigned row = (unsigned)(4 * lane) / 294u;
        unsigned c   = (unsigned)(4 * lane) - row * 294u;
        #pragma unroll
        for (int it = 0; it < 10; ++it) {
            if (it < 9 || lane < 12) {
                unsigned row1 = row, c1 = c + 2;
                if (c1 >= 294u) { c1 -= 294u; row1 += 1; }
                unsigned a0 = c / 42u,  r0 = c - a0 * 42u,  q0 = a0 * 7u + r0 / 6u;
                unsigned a1 = c1 / 42u, r1 = c1 - a1 * 42u, q1 = a1 * 7u + r1 / 6u;
                float qv0 = cbf_s[row * 49 + q0];
                float2 rv0 = *(const float2*)&rbf_s[row * 44 + r0];
                float qv1 = cbf_s[row1 * 49 + q1];
                float2 rv1 = *(const float2*)&rbf_s[row1 * 44 + r1];
                f4 val = { qv0 * rv0.x, qv0 * rv0.y, qv1 * rv1.x, qv1 * rv1.y };
                __builtin_nontemporal_store(val, gT + it * 64 + lane);
            }
            c += 256u; row += 3u;          // +256 chunks*? no: +256 floats = 64 chunks*4
            if (c >= 294u) { c -= 294u; row += 1u; }
            row -= 3u;                     // net: row advances only via the wrap above
        }
        f4* __restrict__ gA = (f4*)(outA + (size_t)t0w * 42);
        #pragma unroll
        for (int it = 0; it < 2; ++it) {
            if (it < 1 || lane < 20) {
                unsigned flat = (unsigned)(4 * (it * 64 + lane));
                unsigned arow = flat / 42u, ac = flat - arow * 42u;
                unsigned arow1 = arow, ac1 = ac + 2;
                if (ac1 >= 42u) { ac1 -= 42u; arow1 += 1; }
                unsigned l0 = ac / 6u,  qa0 = l0 * l0 + l0;
                unsigned l1 = ac1 / 6u, qa1 = l1 * l1 + l1;
                float qv0 = cbf_s[arow * 49 + qa0];
                float2 rv0 = *(const float2*)&rbf_s[arow * 44 + ac];
                float qv1 = cbf_s[arow1 * 49 + qa1];
                float2 rv1 = *(const float2*)&rbf_s[arow1 * 44 + ac1];
                f4 val = { qv0 * rv0.x, qv0 * rv0.y, qv1 * rv1.x, qv1 * rv1.y };
                __builtin_nontemporal_store(val, gA + it * 64 + lane);
            }
        }
    } else {
        // partial tail (not hit when T % 8 == 0) — safe scalar path
        for (int g = lane; g < nvalid * TW; g += 64) {
            int row = g / TW, cc = g - row * TW;
            int a = cc / 42, r = cc - a * 42;
            outT[(size_t)t0w * TW + g] = cbf_s[row * 49 + a * 7 + r / 6] * rbf_s[row * 44 + r];
        }
        for (int g = lane; g < nvalid * 42; g += 64) {
            int row = g / 42, r = g - row * 42;
            int l = r / 6;
            outA[(size_t)t0w * 42 + g] = cbf_s[row * 49 + l * l + l] * rbf_s[row * 44 + r];
        }
    }
}

// ---- host-side double-precision table computation (pure CPU math; graph-safe) ----
static double jl_host(double x, int n) {
    double j0 = sin(x) / x;
    if (n == 0) return j0;
    double jm = j0, j = sin(x) / (x * x) - cos(x) / x;
    for (int l = 2; l <= n; ++l) {
        double t = (2.0 * l - 1.0) / x * j - jm;
        jm = j;
        j = t;
    }
    return j;
}

static void compute_tables(ConstTables* ct) {
    const double PI = 3.14159265358979323846;
    double zeros[NS][12];
    const int total = NK + NS - 1;  // 12
    for (int i = 0; i < total; ++i) zeros[0][i] = (i + 1) * PI;
    for (int l = 1; l < NS; ++l) {
        for (int i = 0; i < total - l; ++i) {
            double a = zeros[l - 1][i], b = zeros[l - 1][i + 1];
            double fa = jl_host(a, l);
            for (int it = 0; it < 100; ++it) {
                double m = 0.5 * (a + b);
                double fm = jl_host(m, l);
                if (fa * fm <= 0.0) b = m;
                else { a = m; fa = fm; }
            }
            zeros[l][i] = 0.5 * (a + b);
        }
    }
    for (int l = 0; l < NS; ++l) {
        for (int i = 0; i < NK; ++i) {
            double z = zeros[l][i];
            double jn1 = jl_host(z, l + 1);
            ct->zc[l * 6 + i] = (float)z;
            ct->nc[l * 6 + i] = (float)(1.0 / sqrt(0.5 * jn1 * jn1));
        }
    }
    double fact[13];
    fact[0] = 1.0;
    for (int i = 1; i < 13; ++i) fact[i] = fact[i - 1] * (double)i;
    ct->Kc[0] = (float)(0.5 / sqrt(PI));
    for (int l = 1; l < NS; ++l) {
        for (int m = -l; m <= l; ++m) {
            int am = m < 0 ? -m : m;
            double K = sqrt((2.0 * l + 1.0) / (4.0 * PI) * fact[l - am] / fact[l + am]);
            if (m != 0) K *= sqrt(2.0);
            ct->Kc[l * l + m + l] = (float)K;
        }
    }
}

extern "C" void kernel_launch(void* const* d_in, const int* in_sizes, int n_in,
                              void* d_out, int out_size, void* d_ws, size_t ws_size,
                              hipStream_t stream) {
    const float* dist    = (const float*)d_in[0];
    const float* angle   = (const float*)d_in[1];
    const float* torsion = (const float*)d_in[2];
    const float* freq    = (const float*)d_in[3];
    const int*   idx_kj  = (const int*)d_in[4];
    const int E = in_sizes[0];
    const int T = in_sizes[1];
    float* out = (float*)d_out;
    float* outA = out + (size_t)E * NK;
    float* outT = outA + (size_t)T * 42;

    ConstTables ct;
    compute_tables(&ct);

    const int NBT = (T + TPB - 1) / TPB;
    const int NBD = (E + 255) / 256;
    fused_kernel<<<NBD + NBT, 256, 0, stream>>>(dist, angle, torsion, freq, idx_kj,
                                                out, outA, outT, E, T, NBD, ct);
}